// Round 2
// baseline (299.410 us; speedup 1.0000x reference)
//
#include <hip/hip_runtime.h>
#include <stdint.h>

#define HASH_BUCKETS 1000
#define EMB_DIM 16
#define HDIM 32
#define G4 128   // 4*HDIM
#define TSTEPS 512
#define BATCH 4096
#define RSTRIDE 40   // dwords per col row: hi[16] | lo[16] | pad[8]

typedef short v8s __attribute__((ext_vector_type(8)));   // 8 bf16 (4 VGPRs)
typedef float v4f __attribute__((ext_vector_type(4)));   // MFMA acc

__device__ __forceinline__ float frcp(float x) {
    float r; asm("v_rcp_f32 %0, %1" : "=v"(r) : "v"(x)); return r;
}
__device__ __forceinline__ float fexp2(float x) {
    float r; asm("v_exp_f32 %0, %1" : "=v"(r) : "v"(x)); return r;
}
// packed f32->bf16 (RNE): dst.lo16 = bf16(a), dst.hi16 = bf16(b)
__device__ __forceinline__ uint32_t cvtpk_bf16(float a, float b) {
    uint32_t r; asm("v_cvt_pk_bf16_f32 %0, %1, %2" : "=v"(r) : "v"(a), "v"(b)); return r;
}
// f32 -> bf16 (RNE), bits in low 16 (A-build only, once per launch)
__device__ __forceinline__ uint32_t bf16rne(float x) {
    uint32_t u = __float_as_uint(x);
    return (u + 0x7FFFu + ((u >> 16) & 1u)) >> 16;
}

// ---------------------------------------------------------------------------
// Kernel 1: embedding folded through input projection, gate exp2-scaling
// folded in: i/f/o rows x (-log2 e), c-row x (+2 log2 e).
// P2[bucket][h][g] = s_g * sum_e emb[bucket][e] * kernel[e][g*32 + h]
// ---------------------------------------------------------------------------
__global__ void precompute_P2_kernel(const float* __restrict__ emb,
                                     const float* __restrict__ kern,
                                     float* __restrict__ P2) {
    int idx = blockIdx.x * blockDim.x + threadIdx.x;
    if (idx >= HASH_BUCKETS * G4) return;
    int row = idx >> 7;
    int c2  = idx & 127;
    int h = c2 >> 2;
    int g = c2 & 3;
    float acc = 0.f;
#pragma unroll
    for (int e = 0; e < EMB_DIM; ++e)
        acc = fmaf(emb[row * EMB_DIM + e], kern[e * G4 + g * 32 + h], acc);
    float sg = (g == 2) ? 2.8853900817779268f : -1.4426950408889634f;
    P2[idx] = acc * sg;
}

// ---------------------------------------------------------------------------
// Kernel 2, this round: 8-wave blocks (512 thr), ONE hidden unit per lane
// (unit = 4w + quad), 2 waves per SIMD so the two chains fill each other's
// latency bubbles. Per-wave: 3 MFMAs, 7 trans, half the gate VALU, one xz
// float4 prefetch. h published pre-split (hi/lo bf16 regions) via 2x
// ds_write_b16 -> reader's 2x ds_read_b128 ARE the Bhi/Blo fragments
// (all 8 v_perms deleted). k-permutation within each 8-block (k = q*8+r+4e)
// is identical on A and B, so MFMA results are unchanged.
// ---------------------------------------------------------------------------
__global__ __launch_bounds__(512)
__attribute__((amdgpu_waves_per_eu(2)))
void lstm_head_kernel(const int* __restrict__ ids,
                      const float* __restrict__ P2,   // [1000][32][4], pre-scaled
                      const float* __restrict__ R,    // rec_kernel [32][128]
                      const float* __restrict__ w1,   // [32][32]
                      const float* __restrict__ b1,   // [32]
                      const float* __restrict__ w2,   // [32]
                      const float* __restrict__ b2,   // [1]
                      float* __restrict__ out) {
    __shared__ __align__(16) uint32_t hbuf[2][16][RSTRIDE];
    __shared__ float hfin[16][33];

    const int tid  = threadIdx.x;
    const int w    = tid >> 6;        // wave 0..7
    const int lane = tid & 63;
    const int col  = lane & 15;       // batch within group
    const int quad = lane >> 4;       // 0..3
    const int bb   = blockIdx.x * 16;
    const int unit = 4 * w + quad;    // this lane's hidden unit
    const int sw   = (col ^ (col >> 2)) & 3;   // bank swizzle key

    const float PL2E   =  2.8853900817779268f;   // 2*log2(e)
    const float NL2E   = -1.4426950408889634f;
    const float N2PL2E = -5.7707801635558536f;   // -2*PL2E

    // ---- A fragment (one 16-row group: units 4w..4w+3 x 4 gates) ----
    union V8 { uint32_t u[4]; v8s v; };
    V8 Ahi, Alo;
    {
        int tt = col >> 2, g = col & 3;
        float sg = (g == 2) ? PL2E : NL2E;
        int gc = g * 32 + 4 * w + tt;
#pragma unroll
        for (int r = 0; r < 4; ++r) {
            uint32_t hp[2], lp[2];
#pragma unroll
            for (int e = 0; e < 2; ++e) {
                int k = quad * 8 + r + 4 * e;   // permuted k-order (matches B)
                float x = R[k * G4 + gc] * sg;
                uint32_t hb = bf16rne(x);
                hp[e] = hb;
                lp[e] = bf16rne(x - __uint_as_float(hb << 16));
            }
            Ahi.u[r] = hp[0] | (hp[1] << 16);
            Alo.u[r] = lp[0] | (lp[1] << 16);
        }
    }

    for (int i = tid; i < 2 * 16 * RSTRIDE; i += 512)
        ((uint32_t*)hbuf)[i] = 0u;

    // ---- read/write addresses (loop-invariant) ----
    // Reader: Bhi = 4 dwords at col row, block (quad^sw); Blo at +16 dwords.
    const uint32_t* rdH[2] = { &hbuf[0][col][4 * (quad ^ sw)],
                               &hbuf[1][col][4 * (quad ^ sw)] };
    // Producer of unit k=4w+quad: hi dword idx = 4*((w>>1)^sw)+quad within
    // the col row's hi region, half = w&1 (low16 = k=8b+r, high16 = k+4).
    uint16_t* base16 = (uint16_t*)&hbuf[0][0][0];
    const int bufhalf = 16 * RSTRIDE * 2;   // 16-bit slots per buffer
    {
    }
    const int hidw = col * RSTRIDE + 4 * (((w >> 1)) ^ sw) + quad;
    const int h16  = hidw * 2 + (w & 1);
    const int l16  = h16 + 32;              // +16 dwords
    uint16_t* wrH[2] = { base16 + bufhalf + h16, base16 + h16 };
    uint16_t* wrL[2] = { base16 + bufhalf + l16, base16 + l16 };

    // ---- deep prefetch pipeline (distance 2) ----
    const int* __restrict__ idrow = ids + (size_t)(bb + col) * TSTEPS;
    int ida = idrow[0];
    float4 xz_c = *(const float4*)(P2 + (size_t)ida * G4 + 4 * unit);
    int idb = idrow[1];
    float4 xz_n = *(const float4*)(P2 + (size_t)idb * G4 + 4 * unit);
    int id_c = idrow[2];
    int id_n = idrow[3];

    float cc = 0.f, hv = 0.f;
    const v4f vzero = {0.f, 0.f, 0.f, 0.f};

    __syncthreads();

    union V8R { uint4 q; v8s v; };

#define STEP(PB, T)                                                             \
    {                                                                           \
        /* B fragments: direct b128 reads, no perms */                          \
        V8R Bhi, Blo;                                                           \
        Bhi.q = *(const uint4*)(rdH[PB]);                                       \
        Blo.q = *(const uint4*)(rdH[PB] + 16);                                  \
        /* issue xz[t+2]; survives raw barriers (no vmcnt drain) */             \
        float4 xz_f = *(const float4*)(P2 + (size_t)id_c * G4 + 4 * unit);      \
        int id_f = idrow[((T) + 4 < TSTEPS) ? ((T) + 4) : (TSTEPS - 1)];        \
        v4f xzv = {xz_c.x, xz_c.y, xz_c.z, xz_c.w};                             \
        v4f ma = __builtin_amdgcn_mfma_f32_16x16x32_bf16(Alo.v, Bhi.v, vzero, 0, 0, 0); \
        v4f mb = __builtin_amdgcn_mfma_f32_16x16x32_bf16(Ahi.v, Blo.v, vzero, 0, 0, 0); \
        v4f mc = __builtin_amdgcn_mfma_f32_16x16x32_bf16(Ahi.v, Bhi.v, xzv, 0, 0, 0);   \
        v4f z = (ma + mb) + mc;                                                 \
        /* z pre-scaled: exp2 directly */                                       \
        float di = 1.f + fexp2(z[0]);                                           \
        float df = 1.f + fexp2(z[1]);                                           \
        float dc = 1.f + fexp2(z[2]);                                           \
        float dq = 1.f + fexp2(z[3]);                                           \
        float Pp = di * df, Qq = dc * dq;                                       \
        float rr = frcp(Pp * Qq);                                               \
        float rP = rr * Qq, rQ = rr * Pp;                                       \
        float ig = rP * df, fg = rP * di, rc = rQ * dq, og = rQ * dc;           \
        float tz = fmaf(N2PL2E, rc, PL2E);   /* PL2E*tanh(zc) */                \
        cc = fmaf(fg, cc, ig * tz);          /* c in PL2E-scaled domain */      \
        float tc = fmaf(-2.f, frcp(1.f + fexp2(cc)), 1.f);                      \
        hv = og * tc;                                                           \
        /* publish: hi bf16 immediately, lo bf16 after */                       \
        uint32_t th = cvtpk_bf16(hv, hv);                                       \
        wrH[PB][0] = (uint16_t)th;                                              \
        float lo = hv - __uint_as_float(th << 16);                              \
        uint32_t tl = cvtpk_bf16(lo, lo);                                       \
        wrL[PB][0] = (uint16_t)tl;                                              \
        xz_c = xz_n; xz_n = xz_f;                                               \
        id_c = id_n; id_n = id_f;                                               \
        /* raw barrier: LDS drain only */                                       \
        asm volatile("s_waitcnt lgkmcnt(0)\n\ts_barrier" ::: "memory");         \
    }

    for (int t = 0; t < TSTEPS; t += 2) {
        STEP(0, t)
        STEP(1, t + 1)
    }
#undef STEP

    // ---- MLP head ----
    hfin[col][unit] = hv;
    __syncthreads();

    int u  = tid & 31;
    int bq = tid >> 5;    // 0..15, single pass with 512 threads
    {
        float y = b1[u];
#pragma unroll
        for (int k = 0; k < HDIM; ++k)
            y = fmaf(hfin[bq][k], w1[k * HDIM + u], y);
        y = fmaxf(y, 0.f);
        float vv = y * w2[u];
#pragma unroll
        for (int off = 16; off >= 1; off >>= 1)
            vv += __shfl_xor(vv, off);
        if (u == 0) out[bb + bq] = vv + b2[0];
    }
}

extern "C" void kernel_launch(void* const* d_in, const int* in_sizes, int n_in,
                              void* d_out, int out_size, void* d_ws, size_t ws_size,
                              hipStream_t stream) {
    const int*   ids  = (const int*)d_in[0];
    const float* emb  = (const float*)d_in[1];
    const float* kern = (const float*)d_in[2];
    const float* rec  = (const float*)d_in[3];
    const float* w1   = (const float*)d_in[4];
    const float* b1   = (const float*)d_in[5];
    const float* w2   = (const float*)d_in[6];
    const float* b2   = (const float*)d_in[7];
    float* out = (float*)d_out;
    float* P2  = (float*)d_ws;   // 512 KB scratch

    precompute_P2_kernel<<<(HASH_BUCKETS * G4 + 255) / 256, 256, 0, stream>>>(
        emb, kern, P2);
    lstm_head_kernel<<<BATCH / 16, 512, 0, stream>>>(
        ids, P2, rec, w1, b1, w2, b2, out);
}